// Round 9
// baseline (263.373 us; speedup 1.0000x reference)
//
#include <hip/hip_runtime.h>
#include <math.h>

#define SCALE 0.36067376022224085f  // 0.25 * log2(e): folded attn scale for exp2-domain softmax

// ws float offsets
#define WVF1F 0      // [32][64] folded ip_w2@wv (layer1)
#define WVF2F 2048   // [32][64] layer2
#define WKT2F 4096   // [64][32] transposed folded ip_w2@wk2 * SCALE (legacy)
#define G1F   6144   // [12][32] g1 (layer-1 score weights)
#define BVF1F 6528   // [64] folded v bias layer1
#define BVF2F 6592   // [64] layer2
// packed float4 weight layouts: P*[jc*4d_stride + d*4 + r] = W[(jc*4+r)*D + d]
#define PQ2   6656
#define PO1   10752
#define PO2   14848
#define PV1   18944
#define PV2   20992
#define PF1   23040
#define PF2   31232
#define POP1  39424
#define PKT2F 41472  // [32j][64D] SCALE * Wkf2 row-major

#define WSYNC() do { asm volatile("s_waitcnt lgkmcnt(0)" ::: "memory"); __builtin_amdgcn_wave_barrier(); } while (0)

struct Params {
  const float* tl; const float* tr; const float* qemb;
  const float* ip_w1; const float* ip_b1;
  const float* bq2;
  const float* bo1; const float* bo2;
  const float* ffn_b1; const float* ffn_b2;
  const float* n1_g; const float* n1_b;
  const float* n2_g; const float* n2_b;
  const float* n3_g; const float* n3_b;
  const float* op_b1;
  const float* op_w2; const float* op_b2;
  const float* ws;
  float* out;
};

__global__ void prep1_kernel(const float* ip_w2, const float* ip_b2,
                             const float* wk2, const float* wv1, const float* wv2,
                             const float* bv1, const float* bv2, float* ws) {
  const int bid = blockIdx.x, tid = threadIdx.x;
  if (bid < 24) {
    const int idx = bid * 256 + tid;
    const int mat = idx >> 11;
    const int rem = idx & 2047;
    const int j = rem >> 6, c = rem & 63;
    const float* W = (mat == 0) ? wv1 : (mat == 1) ? wv2 : wk2;
    float acc = 0.f;
    for (int m = 0; m < 64; ++m) acc = fmaf(ip_w2[j * 64 + m], W[m * 64 + c], acc);
    if (mat == 0)      ws[WVF1F + j * 64 + c] = acc;
    else if (mat == 1) ws[WVF2F + j * 64 + c] = acc;
    else {
      ws[WKT2F + c * 32 + j] = acc * SCALE;
      ws[PKT2F + j * 64 + c] = acc * SCALE;
    }
  } else if (tid < 128) {
    const int l = tid >> 6, d = tid & 63;
    const float* bv = l ? bv2 : bv1;
    const float* wv = l ? wv2 : wv1;
    float acc = bv[d];
    for (int m = 0; m < 64; ++m) acc = fmaf(ip_b2[m], wv[m * 64 + d], acc);
    ws[(l ? BVF2F : BVF1F) + d] = acc;
  }
}

__global__ void prep2_kernel(const float* ip_w2, const float* wk1,
                             const float* qemb, const float* wq1, const float* bq1,
                             float* ws) {
  __shared__ float wkf[32][64];
  __shared__ float q1[3][64];
  const int tid = threadIdx.x;   // 384
  for (int e = tid; e < 2048; e += 384) {
    const int j = e >> 6, c = e & 63;
    float acc = 0.f;
    for (int m = 0; m < 64; ++m) acc = fmaf(ip_w2[j * 64 + m], wk1[m * 64 + c], acc);
    wkf[j][c] = acc;
  }
  if (tid < 192) {
    const int q = tid >> 6, d = tid & 63;
    float acc = bq1[d];
    for (int e = 0; e < 64; ++e) acc = fmaf(qemb[q * 64 + e], wq1[e * 64 + d], acc);
    q1[q][d] = acc;
  }
  __syncthreads();
  {
    const int r = tid >> 5, j = tid & 31;
    const int h = r / 3, q = r - h * 3;
    float acc = 0.f;
    for (int d = 0; d < 16; ++d) acc = fmaf(wkf[j][h * 16 + d], q1[q][h * 16 + d], acc);
    ws[G1F + r * 32 + j] = acc * SCALE;
  }
}

__global__ void prepC_kernel(float* ws,
                             const float* wq2, const float* wo1, const float* wo2,
                             const float* fw1, const float* fw2, const float* opw1) {
  const int e = blockIdx.x * 256 + threadIdx.x;
  if (e >= 34816) return;
  float v; int dst;
  if (e < 4096) {
    const int i = e, jc = i >> 8, rem = i & 255, d = rem >> 2, r = rem & 3;
    v = wq2[(jc * 4 + r) * 64 + d]; dst = PQ2 + i;
  } else if (e < 8192) {
    const int i = e - 4096, jc = i >> 8, rem = i & 255, d = rem >> 2, r = rem & 3;
    v = wo1[(jc * 4 + r) * 64 + d]; dst = PO1 + i;
  } else if (e < 12288) {
    const int i = e - 8192, jc = i >> 8, rem = i & 255, d = rem >> 2, r = rem & 3;
    v = wo2[(jc * 4 + r) * 64 + d]; dst = PO2 + i;
  } else if (e < 14336) {
    const int i = e - 12288, jc = i >> 8, rem = i & 255, d = rem >> 2, r = rem & 3;
    v = ws[WVF1F + (jc * 4 + r) * 64 + d]; dst = PV1 + i;
  } else if (e < 16384) {
    const int i = e - 14336, jc = i >> 8, rem = i & 255, d = rem >> 2, r = rem & 3;
    v = ws[WVF2F + (jc * 4 + r) * 64 + d]; dst = PV2 + i;
  } else if (e < 24576) {
    const int i = e - 16384, jc = i >> 9, rem = i & 511, d = rem >> 2, r = rem & 3;
    v = fw1[(jc * 4 + r) * 128 + d]; dst = PF1 + i;
  } else if (e < 32768) {
    const int i = e - 24576, mc = i >> 8, rem = i & 255, d = rem >> 2, r = rem & 3;
    v = fw2[(mc * 4 + r) * 64 + d]; dst = PF2 + i;
  } else {
    const int i = e - 32768, jc = i >> 7, rem = i & 127, d = rem >> 2, r = rem & 3;
    v = opw1[(jc * 4 + r) * 32 + d]; dst = POP1 + i;
  }
  ws[dst] = v;
}

// 1 wave/block, 2 items/wave. Both items' work sits inside each barrier-free
// region -> 2x independent ILP fills lgkmcnt/FMA-latency stalls; weight loads
// amortized over 6 q-rows. LDS 14.5KB -> ~11 blocks(waves)/CU.
__global__ __launch_bounds__(64) void planner_kernel(Params p) {
  const int lane = threadIdx.x;
  const int itemBase = blockIdx.x * 2;

  __shared__ __align__(16) float a_s[2][20][36];   // acts; later f1 overlay [3][136]
  __shared__ __align__(16) float att_s[2][12][20]; // scores -> normalized probs
  __shared__ __align__(16) float ch_s[2][12][36];  // att@a; also g2
  __shared__ __align__(16) float qx_s[2][3][64];   // q2 / o / y1
  __shared__ __align__(16) float x_s[2][3][64];    // residual stream
  __shared__ __align__(16) float pts_s[2][40];

  const float* ws = p.ws;

  // stage points (80 floats)
#pragma unroll
  for (int pass = 0; pass < 2; ++pass) {
    const int idx = pass * 64 + lane;
    if (idx < 80) {
      const int i = idx / 40, r = idx - 40 * i;
      pts_s[i][r] = (r < 20) ? p.tl[(itemBase + i) * 20 + r]
                             : p.tr[(itemBase + i) * 20 + r - 20];
    }
  }
  WSYNC();

  // ip MLP -> a
  {
    const int j = lane & 31, th = lane >> 5;
    const float w0 = p.ip_w1[j], w1 = p.ip_w1[32 + j], b = p.ip_b1[j];
#pragma unroll
    for (int it = 0; it < 2; ++it)
#pragma unroll
      for (int i = 0; i < 10; ++i) {
        const int t = th * 10 + i;
        a_s[it][t][j] =
            fmaxf(fmaf(pts_s[it][2 * t], w0, fmaf(pts_s[it][2 * t + 1], w1, b)), 0.f);
      }
  }
  WSYNC();

  const int t3 = lane / 3, q3 = lane - t3 * 3;
  const int j32 = lane & 31, half = lane >> 5, hq0 = half * 6;
  const int h16 = lane >> 4;
  const int r12 = lane >> 2, sub = lane & 3;

  float xq[2][3];

#pragma unroll
  for (int l = 0; l < 2; ++l) {
    if (l == 1) {
      // ---- Q2 = x1 @ wq2 + bq2 ----
      {
        const float bq = p.bq2[lane];
        float acc[2][3];
#pragma unroll
        for (int it = 0; it < 2; ++it)
#pragma unroll
          for (int q = 0; q < 3; ++q) acc[it][q] = bq;
#pragma unroll
        for (int jc = 0; jc < 16; ++jc) {
          const float4 w4 = *(const float4*)&ws[PQ2 + jc * 256 + lane * 4];
#pragma unroll
          for (int it = 0; it < 2; ++it)
#pragma unroll
            for (int q = 0; q < 3; ++q) {
              const float4 xv = *(const float4*)&x_s[it][q][jc * 4];
              acc[it][q] = fmaf(xv.x, w4.x, fmaf(xv.y, w4.y,
                            fmaf(xv.z, w4.z, fmaf(xv.w, w4.w, acc[it][q]))));
            }
        }
#pragma unroll
        for (int it = 0; it < 2; ++it)
#pragma unroll
          for (int q = 0; q < 3; ++q) qx_s[it][q][lane] = acc[it][q];
      }
      WSYNC();
      // ---- g2 = q2 @ (SCALE*Wkf2^T), packed float4 ----
      {
        float g2[2][6];
#pragma unroll
        for (int it = 0; it < 2; ++it)
#pragma unroll
          for (int k = 0; k < 6; ++k) g2[it][k] = 0.f;
        const int D0 = half * 32;
        const float* pkt = &ws[PKT2F + j32 * 64 + D0];
#pragma unroll
        for (int dd = 0; dd < 8; ++dd) {
          const float4 wk4 = *(const float4*)&pkt[dd * 4];
          const int hl = dd >> 2;
#pragma unroll
          for (int it = 0; it < 2; ++it)
#pragma unroll
            for (int q = 0; q < 3; ++q) {
              const float4 q4 = *(const float4*)&qx_s[it][q][D0 + dd * 4];
              g2[it][hl * 3 + q] = fmaf(q4.x, wk4.x, fmaf(q4.y, wk4.y,
                                     fmaf(q4.z, wk4.z, fmaf(q4.w, wk4.w, g2[it][hl * 3 + q]))));
            }
        }
#pragma unroll
        for (int it = 0; it < 2; ++it)
#pragma unroll
          for (int k = 0; k < 6; ++k) ch_s[it][hq0 + k][j32] = g2[it][k];
      }
      WSYNC();
    }

    // ---- scores: lane=(t,q), s[h] = sum_j a[t][j]*g[h*3+q][j] ----
    if (lane < 60) {
      float acc[2][4];
#pragma unroll
      for (int it = 0; it < 2; ++it)
#pragma unroll
        for (int h = 0; h < 4; ++h) acc[it][h] = 0.f;
      if (l == 0) {
        // g1 broadcast from global (L1-resident, 1.5KB), shared by both items
#pragma unroll
        for (int jc = 0; jc < 8; ++jc) {
          float4 g4[4];
#pragma unroll
          for (int h = 0; h < 4; ++h)
            g4[h] = *(const float4*)&ws[G1F + (h * 3 + q3) * 32 + jc * 4];
#pragma unroll
          for (int it = 0; it < 2; ++it) {
            const float4 av = *(const float4*)&a_s[it][t3][jc * 4];
#pragma unroll
            for (int h = 0; h < 4; ++h)
              acc[it][h] = fmaf(av.x, g4[h].x, fmaf(av.y, g4[h].y,
                             fmaf(av.z, g4[h].z, fmaf(av.w, g4[h].w, acc[it][h]))));
          }
        }
      } else {
#pragma unroll
        for (int it = 0; it < 2; ++it)
#pragma unroll
          for (int jc = 0; jc < 8; ++jc) {
            const float4 av = *(const float4*)&a_s[it][t3][jc * 4];
#pragma unroll
            for (int h = 0; h < 4; ++h) {
              const float4 gv = *(const float4*)&ch_s[it][h * 3 + q3][jc * 4];
              acc[it][h] = fmaf(av.x, gv.x, fmaf(av.y, gv.y,
                             fmaf(av.z, gv.z, fmaf(av.w, gv.w, acc[it][h]))));
            }
          }
      }
#pragma unroll
      for (int it = 0; it < 2; ++it)
#pragma unroll
        for (int h = 0; h < 4; ++h) att_s[it][h * 3 + q3][t3] = acc[it][h];
    }
    WSYNC();

    // ---- wave-parallel softmax: 4 lanes/row x 5 t ----
    if (r12 < 12) {
      const int tb = sub * 5;
#pragma unroll
      for (int it = 0; it < 2; ++it) {
        float v0 = att_s[it][r12][tb],     v1 = att_s[it][r12][tb + 1];
        float v2 = att_s[it][r12][tb + 2], v3 = att_s[it][r12][tb + 3];
        float v4 = att_s[it][r12][tb + 4];
        float m = fmaxf(fmaxf(fmaxf(v0, v1), fmaxf(v2, v3)), v4);
        m = fmaxf(m, __shfl_xor(m, 1));
        m = fmaxf(m, __shfl_xor(m, 2));
        v0 = exp2f(v0 - m); v1 = exp2f(v1 - m); v2 = exp2f(v2 - m);
        v3 = exp2f(v3 - m); v4 = exp2f(v4 - m);
        float s = v0 + v1 + v2 + v3 + v4;
        s += __shfl_xor(s, 1);
        s += __shfl_xor(s, 2);
        const float inv = 1.f / s;
        att_s[it][r12][tb]     = v0 * inv;
        att_s[it][r12][tb + 1] = v1 * inv;
        att_s[it][r12][tb + 2] = v2 * inv;
        att_s[it][r12][tb + 3] = v3 * inv;
        att_s[it][r12][tb + 4] = v4 * inv;
      }
    }
    WSYNC();

    // ---- ch[hq][j] = sum_t att[hq][t]*a[t][j] ----
    {
      float c[2][6];
#pragma unroll
      for (int it = 0; it < 2; ++it)
#pragma unroll
        for (int k = 0; k < 6; ++k) c[it][k] = 0.f;
#pragma unroll
      for (int tc = 0; tc < 5; ++tc)
#pragma unroll
        for (int it = 0; it < 2; ++it) {
          float av[4];
#pragma unroll
          for (int r = 0; r < 4; ++r) av[r] = a_s[it][tc * 4 + r][j32];
#pragma unroll
          for (int k = 0; k < 6; ++k) {
            const float4 at = *(const float4*)&att_s[it][hq0 + k][tc * 4];
            c[it][k] = fmaf(at.x, av[0], fmaf(at.y, av[1],
                        fmaf(at.z, av[2], fmaf(at.w, av[3], c[it][k]))));
          }
        }
#pragma unroll
      for (int it = 0; it < 2; ++it)
#pragma unroll
        for (int k = 0; k < 6; ++k) ch_s[it][hq0 + k][j32] = c[it][k];
    }
    WSYNC();

    // ---- o[q][d] = sum_j ch[h(d)*3+q][j]*Wvf[j][d] + bvf[d] ----
    {
      const int pvo = l ? PV2 : PV1;
      const float bv = ws[(l ? BVF2F : BVF1F) + lane];
      float o[2][3];
#pragma unroll
      for (int it = 0; it < 2; ++it)
#pragma unroll
        for (int q = 0; q < 3; ++q) o[it][q] = bv;
#pragma unroll
      for (int jc = 0; jc < 8; ++jc) {
        const float4 w4 = *(const float4*)&ws[pvo + jc * 256 + lane * 4];
#pragma unroll
        for (int it = 0; it < 2; ++it)
#pragma unroll
          for (int q = 0; q < 3; ++q) {
            const float4 cv = *(const float4*)&ch_s[it][h16 * 3 + q][jc * 4];
            o[it][q] = fmaf(cv.x, w4.x, fmaf(cv.y, w4.y,
                        fmaf(cv.z, w4.z, fmaf(cv.w, w4.w, o[it][q]))));
          }
      }
#pragma unroll
      for (int it = 0; it < 2; ++it)
#pragma unroll
        for (int q = 0; q < 3; ++q) qx_s[it][q][lane] = o[it][q];
    }
    WSYNC();

    // ---- O-proj + residual + LN ----
    {
      const int poo = l ? PO2 : PO1;
      const float bo = (l ? p.bo2 : p.bo1)[lane];
      float acc[2][3];
#pragma unroll
      for (int it = 0; it < 2; ++it)
#pragma unroll
        for (int q = 0; q < 3; ++q)
          acc[it][q] = bo + (l ? xq[it][q] : p.qemb[q * 64 + lane]);
#pragma unroll
      for (int jc = 0; jc < 16; ++jc) {
        const float4 w4 = *(const float4*)&ws[poo + jc * 256 + lane * 4];
#pragma unroll
        for (int it = 0; it < 2; ++it)
#pragma unroll
          for (int q = 0; q < 3; ++q) {
            const float4 ov = *(const float4*)&qx_s[it][q][jc * 4];
            acc[it][q] = fmaf(ov.x, w4.x, fmaf(ov.y, w4.y,
                          fmaf(ov.z, w4.z, fmaf(ov.w, w4.w, acc[it][q]))));
          }
      }
      const float gv = (l ? p.n2_g : p.n1_g)[lane];
      const float gb = (l ? p.n2_b : p.n1_b)[lane];
#pragma unroll
      for (int it = 0; it < 2; ++it)
#pragma unroll
        for (int q = 0; q < 3; ++q) {
          const float v = acc[it][q];
          float s = v;
#pragma unroll
          for (int m = 32; m >= 1; m >>= 1) s += __shfl_xor(s, m);
          const float mu = s * (1.f / 64.f);
          const float d = v - mu;
          float s2 = d * d;
#pragma unroll
          for (int m = 32; m >= 1; m >>= 1) s2 += __shfl_xor(s2, m);
          const float inv = rsqrtf(s2 * (1.f / 64.f) + 1e-5f);
          const float xn = fmaf(d * inv, gv, gb);
          xq[it][q] = xn;
          x_s[it][q][lane] = xn;
        }
    }
    WSYNC();
  }

  // ---- FFN1 -> f1 overlay on a_s ----
  float* f1base = (float*)a_s;   // two [3][136] blocks at offsets 0 / 720
  {
    const float b0 = p.ffn_b1[lane], b1 = p.ffn_b1[64 + lane];
    float a0[2][3], a1[2][3];
#pragma unroll
    for (int it = 0; it < 2; ++it)
#pragma unroll
      for (int q = 0; q < 3; ++q) { a0[it][q] = b0; a1[it][q] = b1; }
#pragma unroll
    for (int jc = 0; jc < 16; ++jc) {
      const float4 w04 = *(const float4*)&ws[PF1 + jc * 512 + lane * 4];
      const float4 w14 = *(const float4*)&ws[PF1 + jc * 512 + 256 + lane * 4];
#pragma unroll
      for (int it = 0; it < 2; ++it)
#pragma unroll
        for (int q = 0; q < 3; ++q) {
          const float4 xv = *(const float4*)&x_s[it][q][jc * 4];
          a0[it][q] = fmaf(xv.x, w04.x, fmaf(xv.y, w04.y,
                        fmaf(xv.z, w04.z, fmaf(xv.w, w04.w, a0[it][q]))));
          a1[it][q] = fmaf(xv.x, w14.x, fmaf(xv.y, w14.y,
                        fmaf(xv.z, w14.z, fmaf(xv.w, w14.w, a1[it][q]))));
        }
    }
#pragma unroll
    for (int it = 0; it < 2; ++it) {
      float* f1p = f1base + it * 720;
#pragma unroll
      for (int q = 0; q < 3; ++q) {
        f1p[q * 136 + lane] = fmaxf(a0[it][q], 0.f);
        f1p[q * 136 + 64 + lane] = fmaxf(a1[it][q], 0.f);
      }
    }
  }
  WSYNC();

  // ---- FFN2 + residual + LN3 ----
  {
    const float fb2 = p.ffn_b2[lane];
    float acc[2][3];
#pragma unroll
    for (int it = 0; it < 2; ++it)
#pragma unroll
      for (int q = 0; q < 3; ++q) acc[it][q] = fb2 + xq[it][q];
#pragma unroll
    for (int mc = 0; mc < 32; ++mc) {
      const float4 w4 = *(const float4*)&ws[PF2 + mc * 256 + lane * 4];
#pragma unroll
      for (int it = 0; it < 2; ++it)
#pragma unroll
        for (int q = 0; q < 3; ++q) {
          const float4 fv = *(const float4*)&f1base[it * 720 + q * 136 + mc * 4];
          acc[it][q] = fmaf(fv.x, w4.x, fmaf(fv.y, w4.y,
                        fmaf(fv.z, w4.z, fmaf(fv.w, w4.w, acc[it][q]))));
        }
    }
    const float gv = p.n3_g[lane], gb = p.n3_b[lane];
#pragma unroll
    for (int it = 0; it < 2; ++it)
#pragma unroll
      for (int q = 0; q < 3; ++q) {
        const float v = acc[it][q];
        float s = v;
#pragma unroll
        for (int m = 32; m >= 1; m >>= 1) s += __shfl_xor(s, m);
        const float mu = s * (1.f / 64.f);
        const float d = v - mu;
        float s2 = d * d;
#pragma unroll
        for (int m = 32; m >= 1; m >>= 1) s2 += __shfl_xor(s2, m);
        const float inv = rsqrtf(s2 * (1.f / 64.f) + 1e-5f);
        x_s[it][q][lane] = fmaf(d * inv, gv, gb);
      }
  }
  WSYNC();

  // ---- head1: y1 = relu(x3 @ op_w1 + op_b1) [3][32] ----
  if (lane < 32) {
    const float ob = p.op_b1[lane];
    float acc[2][3];
#pragma unroll
    for (int it = 0; it < 2; ++it)
#pragma unroll
      for (int q = 0; q < 3; ++q) acc[it][q] = ob;
#pragma unroll
    for (int jc = 0; jc < 16; ++jc) {
      const float4 w4 = *(const float4*)&ws[POP1 + jc * 128 + lane * 4];
#pragma unroll
      for (int it = 0; it < 2; ++it)
#pragma unroll
        for (int q = 0; q < 3; ++q) {
          const float4 xv = *(const float4*)&x_s[it][q][jc * 4];
          acc[it][q] = fmaf(xv.x, w4.x, fmaf(xv.y, w4.y,
                        fmaf(xv.z, w4.z, fmaf(xv.w, w4.w, acc[it][q]))));
        }
    }
#pragma unroll
    for (int it = 0; it < 2; ++it)
#pragma unroll
      for (int q = 0; q < 3; ++q) qx_s[it][q][lane] = fmaxf(acc[it][q], 0.f);
  }
  WSYNC();

  // ---- head2: lanes 0..47, 24 per item, quad reduce ----
  if (lane < 48) {
    const int it = lane >= 24;
    const int ll = lane - 24 * it;
    const int q = ll >> 3, e = (ll >> 2) & 1, mg = ll & 3;
    float acc = 0.f;
#pragma unroll
    for (int k = 0; k < 8; ++k) {
      const int m = mg * 8 + k;
      acc = fmaf(qx_s[it][q][m], p.op_w2[m * 2 + e], acc);
    }
    acc += __shfl_xor(acc, 1);
    acc += __shfl_xor(acc, 2);
    if (mg == 0)
      p.out[(itemBase + it) * 6 + q * 2 + e] = acc + p.op_b2[e];
  }
}

extern "C" void kernel_launch(void* const* d_in, const int* in_sizes, int n_in,
                              void* d_out, int out_size, void* d_ws, size_t ws_size,
                              hipStream_t stream) {
  const float* in[40];
  for (int i = 0; i < n_in && i < 40; ++i) in[i] = (const float*)d_in[i];

  const float *a1_wq, *a1_wk, *a1_wv, *a1_wo, *a1_bq, *a1_bk, *a1_bv, *a1_bo;
  const float *a2_wq, *a2_wk, *a2_wv, *a2_wo, *a2_bq, *a2_bk, *a2_bv, *a2_bo;
  if (in_sizes[8] == 4096) {
    a1_wq = in[7];  a1_wk = in[8];  a1_wv = in[9];  a1_wo = in[10];
    a1_bq = in[11]; a1_bk = in[12]; a1_bv = in[13]; a1_bo = in[14];
    a2_wq = in[15]; a2_wk = in[16]; a2_wv = in[17]; a2_wo = in[18];
    a2_bq = in[19]; a2_bk = in[20]; a2_bv = in[21]; a2_bo = in[22];
  } else {
    a1_wq = in[7];  a1_bq = in[8];  a1_wk = in[9];  a1_bk = in[10];
    a1_wv = in[11]; a1_bv = in[12]; a1_wo = in[13]; a1_bo = in[14];
    a2_wq = in[15]; a2_bq = in[16]; a2_wk = in[17]; a2_bk = in[18];
    a2_wv = in[19]; a2_bv = in[20]; a2_wo = in[21]; a2_bo = in[22];
  }
  (void)a1_bk; (void)a2_bk;  // K biases fold out of softmax exactly

  float* ws = (float*)d_ws;
  prep1_kernel<<<25, 256, 0, stream>>>(in[5], in[6], a2_wk, a1_wv, a2_wv, a1_bv, a2_bv, ws);
  prep2_kernel<<<1, 384, 0, stream>>>(in[5], a1_wk, in[2], a1_wq, a1_bq, ws);
  prepC_kernel<<<136, 256, 0, stream>>>(ws, a2_wq, a1_wo, a2_wo, in[23], in[25], in[33]);

  Params p;
  p.tl = in[0]; p.tr = in[1]; p.qemb = in[2];
  p.ip_w1 = in[3]; p.ip_b1 = in[4];
  p.bq2 = a2_bq;
  p.bo1 = a1_bo; p.bo2 = a2_bo;
  p.ffn_b1 = in[24]; p.ffn_b2 = in[26];
  p.n1_g = in[27]; p.n1_b = in[28]; p.n2_g = in[29]; p.n2_b = in[30];
  p.n3_g = in[31]; p.n3_b = in[32];
  p.op_b1 = in[34]; p.op_w2 = in[35]; p.op_b2 = in[36];
  p.ws = ws; p.out = (float*)d_out;

  planner_kernel<<<16384, 64, 0, stream>>>(p);
}